// Round 1
// 464.889 us; speedup vs baseline: 1.0287x; 1.0287x over previous
//
#include <hip/hip_runtime.h>
#include <hip/hip_bf16.h>
#include <math.h>

#define NUM_USERS  100000
#define NUM_ITEMS  50000
#define N_NODES    150000
#define EMBED_DIM  64
#define NUM_EDGES  1250000
#define MLP_HID    32
#define SCAN_B     1024
#define SCAN_NB    ((N_NODES + SCAN_B - 1) / SCAN_B)   // 147

// ---------------------------------------------------------------------------
// Kernel 1: histogram of cols + within-bucket rank (atomic return value IS
// the rank -> downstream scatter needs no atomics).
// ---------------------------------------------------------------------------
__global__ void hist_rank(const int* __restrict__ edge_index,
                          int* __restrict__ cnt,
                          int* __restrict__ rank) {
    int e = blockIdx.x * blockDim.x + threadIdx.x;
    if (e >= NUM_EDGES) return;
    int c = edge_index[NUM_EDGES + e];
    rank[e] = atomicAdd(&cnt[c], 1);
}

// ---------------------------------------------------------------------------
// Device-wide exclusive scan of cnt -> row_ptr, 3 phases.
// ---------------------------------------------------------------------------
__global__ void scan_partial(const int* __restrict__ cnt,
                             int* __restrict__ part) {
    __shared__ int s[SCAN_B];
    int tid = threadIdx.x;
    int i = blockIdx.x * SCAN_B + tid;
    s[tid] = (i < N_NODES) ? cnt[i] : 0;
    __syncthreads();
#pragma unroll
    for (int off = SCAN_B / 2; off > 0; off >>= 1) {
        if (tid < off) s[tid] += s[tid + off];
        __syncthreads();
    }
    if (tid == 0) part[blockIdx.x] = s[0];
}

__global__ void scan_offsets(const int* __restrict__ part,
                             int* __restrict__ base_off) {
    __shared__ int s[256];
    int tid = threadIdx.x;
    int v = (tid < SCAN_NB) ? part[tid] : 0;
    s[tid] = v;
    __syncthreads();
#pragma unroll
    for (int off = 1; off < 256; off <<= 1) {
        int t = (tid >= off) ? s[tid - off] : 0;
        __syncthreads();
        s[tid] += t;
        __syncthreads();
    }
    if (tid < SCAN_NB) base_off[tid] = s[tid] - v;   // exclusive
}

__global__ void scan_apply(const int* __restrict__ cnt,
                           const int* __restrict__ base_off,
                           int* __restrict__ row_ptr) {
    __shared__ int s[SCAN_B];
    int tid = threadIdx.x;
    int i = blockIdx.x * SCAN_B + tid;
    int v = (i < N_NODES) ? cnt[i] : 0;
    s[tid] = v;
    __syncthreads();
    for (int off = 1; off < SCAN_B; off <<= 1) {
        int t = (tid >= off) ? s[tid - off] : 0;
        __syncthreads();
        s[tid] += t;
        __syncthreads();
    }
    if (i < N_NODES) row_ptr[i] = s[tid] - v + base_off[blockIdx.x];
    if (blockIdx.x == 0 && tid == 0) row_ptr[N_NODES] = NUM_EDGES;
}

// ---------------------------------------------------------------------------
// Kernel 2: per-edge MLP fused with ATOMIC-FREE CSR scatter.
// ---------------------------------------------------------------------------
__global__ void mlp_scatter(const float* __restrict__ edge_attr,
                            const float* __restrict__ ew,
                            const float* __restrict__ w1,
                            const float* __restrict__ b1,
                            const float* __restrict__ w2,
                            const float* __restrict__ b2,
                            const int*   __restrict__ edge_index,
                            const int*   __restrict__ rank,
                            const int*   __restrict__ row_ptr,
                            int2* __restrict__ csr_pair) {
    __shared__ float w1s[8 * MLP_HID];
    __shared__ float b1s[MLP_HID];
    __shared__ float w2s[MLP_HID];
    int tid = threadIdx.x;
    if (tid < 8 * MLP_HID) w1s[tid] = w1[tid];
    if (tid < MLP_HID) { b1s[tid] = b1[tid]; w2s[tid] = w2[tid]; }
    __syncthreads();

    int e = blockIdx.x * blockDim.x + tid;
    if (e >= NUM_EDGES) return;

    float ef[8];
#pragma unroll
    for (int k = 0; k < 7; ++k) ef[k] = edge_attr[e * 7 + k];
    ef[7] = ew[e];

    float s = b2[0];
#pragma unroll
    for (int j = 0; j < MLP_HID; ++j) {
        float h = b1s[j];
#pragma unroll
        for (int k = 0; k < 8; ++k) h = fmaf(ef[k], w1s[k * MLP_HID + j], h);
        h = fmaxf(h, 0.0f);
        s = fmaf(h, w2s[j], s);
    }
    float w = 1.0f / (1.0f + expf(-s));

    int r = edge_index[e];
    int c = edge_index[NUM_EDGES + e];
    int pos = row_ptr[c] + rank[e];
    int2 pr;
    pr.x = r;
    pr.y = __float_as_int(w);
    csr_pair[pos] = pr;
}

// ---------------------------------------------------------------------------
// deg[node] = segment sum of pair.w bucket; 16 lanes/node (avg deg 8.3).
// ---------------------------------------------------------------------------
__global__ void deg_dinv_csr(const int* __restrict__ row_ptr,
                             const int2* __restrict__ csr_pair,
                             float* __restrict__ dinv) {
    int t = blockIdx.x * blockDim.x + threadIdx.x;
    int node = t >> 4;
    int lane = t & 15;
    if (node >= N_NODES) return;
    int s = row_ptr[node], e = row_ptr[node + 1];
    float sum = 0.0f;
    for (int j = s + lane; j < e; j += 16) sum += __int_as_float(csr_pair[j].y);
    sum += __shfl_xor(sum, 8);
    sum += __shfl_xor(sum, 4);
    sum += __shfl_xor(sum, 2);
    sum += __shfl_xor(sum, 1);
    if (lane == 0)
        dinv[node] = (sum > 0.0f) ? rsqrtf(fmaxf(sum, 1e-30f)) : 0.0f;
}

// ---------------------------------------------------------------------------
// pair.w *= dinv[col] * dinv[pair.src]   16 lanes/node.
// ---------------------------------------------------------------------------
__global__ void csr_scale(const int* __restrict__ row_ptr,
                          const float* __restrict__ dinv,
                          int2* __restrict__ csr_pair) {
    int t = blockIdx.x * blockDim.x + threadIdx.x;
    int node = t >> 4;
    int lane = t & 15;
    if (node >= N_NODES) return;
    int s = row_ptr[node], e = row_ptr[node + 1];
    float dc = dinv[node];
    for (int j = s + lane; j < e; j += 16) {
        int2 p = csr_pair[j];
        p.y = __float_as_int(__int_as_float(p.y) * dc * dinv[p.x]);
        csr_pair[j] = p;
    }
}

// ---------------------------------------------------------------------------
// build x0: bf16 only.
// ---------------------------------------------------------------------------
__global__ void init_x(const float* __restrict__ user_w,
                       const float* __restrict__ artist_w,
                       const float* __restrict__ album_w,
                       const float* __restrict__ audio,
                       const int*   __restrict__ artist_ids,
                       const int*   __restrict__ album_ids,
                       __hip_bfloat16* __restrict__ x) {
    int t = blockIdx.x * blockDim.x + threadIdx.x;
    int row = t >> 6;
    int lane = t & 63;
    if (row >= N_NODES) return;

    float v;
    if (row < NUM_USERS) {
        v = user_w[row * EMBED_DIM + lane];
    } else {
        int r = row - NUM_USERS;
        int ar = artist_ids[r];
        int al = album_ids[r];
        v = audio[r * EMBED_DIM + lane]
          + 0.5f * (artist_w[ar * EMBED_DIM + lane] + album_w[al * EMBED_DIM + lane]);
    }
    float ss = v * v;
#pragma unroll
    for (int off = 32; off > 0; off >>= 1) ss += __shfl_xor(ss, off);
    float scale = 1.0f / fmaxf(sqrtf(ss), 1e-12f);
    x[row * EMBED_DIM + lane] = __float2bfloat16(v * scale);
}

// ---------------------------------------------------------------------------
// pull-mode propagation, 4 edge slots x 16 dim-lanes (4 dims/lane, uint2).
// Butterfly reduce = 4 accs x 2 rounds = 16 instrs (was 48).
// csr_pair software-pipelined: next pair load issues before current FMAs.
// Out-of-range prefetches stay inside the workspace (csr_pair is followed by
// the dinv region), and src/nw are cndmask-guarded -> no fault, no effect.
// ---------------------------------------------------------------------------
__global__ void propagate_mid(const int* __restrict__ row_ptr,
                              const int2* __restrict__ csr_pair,
                              const unsigned short* __restrict__ xin,
                              unsigned short* __restrict__ xout) {
    int t = blockIdx.x * blockDim.x + threadIdx.x;
    int node = t >> 6;
    int lane = t & 63;
    if (node >= N_NODES) return;

    int start = row_ptr[node];
    int end   = row_ptr[node + 1];

    int eg = lane >> 4;          // edge slot 0..3
    int dq = (lane & 15) << 2;   // dim quad start

    float a0 = 0, a1 = 0, a2 = 0, a3 = 0;

    int j = start + eg;
    int2 p = csr_pair[j];        // prefetch (safe even if row empty)

    for (int base = start; base < end; base += 4) {
        bool ok = (base + eg < end);
        int   src = ok ? p.x : 0;
        float nw  = ok ? __int_as_float(p.y) : 0.0f;
        uint2 u = *(const uint2*)(xin + ((size_t)src << 6) + dq);
        j += 4;
        int2 pn = csr_pair[j];   // prefetch next, overlaps with gather+fma
        a0 = fmaf(nw, __uint_as_float(u.x << 16),         a0);
        a1 = fmaf(nw, __uint_as_float(u.x & 0xffff0000u), a1);
        a2 = fmaf(nw, __uint_as_float(u.y << 16),         a2);
        a3 = fmaf(nw, __uint_as_float(u.y & 0xffff0000u), a3);
        p = pn;
    }

    a0 += __shfl_xor(a0, 16); a1 += __shfl_xor(a1, 16);
    a2 += __shfl_xor(a2, 16); a3 += __shfl_xor(a3, 16);
    a0 += __shfl_xor(a0, 32); a1 += __shfl_xor(a1, 32);
    a2 += __shfl_xor(a2, 32); a3 += __shfl_xor(a3, 32);

    if (eg == 0) {
        size_t o = ((size_t)node << 6) + dq;
        unsigned int b0 = (unsigned int)__bfloat16_as_ushort(__float2bfloat16(a0));
        unsigned int b1 = (unsigned int)__bfloat16_as_ushort(__float2bfloat16(a1));
        unsigned int b2 = (unsigned int)__bfloat16_as_ushort(__float2bfloat16(a2));
        unsigned int b3 = (unsigned int)__bfloat16_as_ushort(__float2bfloat16(a3));
        uint2 u;
        u.x = b0 | (b1 << 16);
        u.y = b2 | (b3 << 16);
        *(uint2*)(xout + o) = u;
    }
}

// ---------------------------------------------------------------------------
// FINAL layer: gather from x2, then out = l2norm((x0+x1+x2+a)/4), f32.
// Same 4x16 layout; merge + l2norm run on the 16 dim-lanes.
// ---------------------------------------------------------------------------
__global__ void propagate_final(const int* __restrict__ row_ptr,
                                const int2* __restrict__ csr_pair,
                                const unsigned short* __restrict__ x0,
                                const unsigned short* __restrict__ x1,
                                const unsigned short* __restrict__ x2,
                                float* __restrict__ outp) {
    int t = blockIdx.x * blockDim.x + threadIdx.x;
    int node = t >> 6;
    int lane = t & 63;
    if (node >= N_NODES) return;

    int start = row_ptr[node];
    int end   = row_ptr[node + 1];

    int eg = lane >> 4;
    int dq = (lane & 15) << 2;

    float a0 = 0, a1 = 0, a2 = 0, a3 = 0;

    int j = start + eg;
    int2 p = csr_pair[j];

    for (int base = start; base < end; base += 4) {
        bool ok = (base + eg < end);
        int   src = ok ? p.x : 0;
        float nw  = ok ? __int_as_float(p.y) : 0.0f;
        uint2 u = *(const uint2*)(x2 + ((size_t)src << 6) + dq);
        j += 4;
        int2 pn = csr_pair[j];
        a0 = fmaf(nw, __uint_as_float(u.x << 16),         a0);
        a1 = fmaf(nw, __uint_as_float(u.x & 0xffff0000u), a1);
        a2 = fmaf(nw, __uint_as_float(u.y << 16),         a2);
        a3 = fmaf(nw, __uint_as_float(u.y & 0xffff0000u), a3);
        p = pn;
    }

    a0 += __shfl_xor(a0, 16); a1 += __shfl_xor(a1, 16);
    a2 += __shfl_xor(a2, 16); a3 += __shfl_xor(a3, 16);
    a0 += __shfl_xor(a0, 32); a1 += __shfl_xor(a1, 32);
    a2 += __shfl_xor(a2, 32); a3 += __shfl_xor(a3, 32);

    if (eg == 0) {
        size_t o = ((size_t)node << 6) + dq;
        uint2 u0 = *(const uint2*)(x0 + o);
        uint2 u1 = *(const uint2*)(x1 + o);
        uint2 u2 = *(const uint2*)(x2 + o);

#define BF_LO(u) __uint_as_float((u) << 16)
#define BF_HI(u) __uint_as_float((u) & 0xffff0000u)
        float v0 = (BF_LO(u0.x) + BF_LO(u1.x) + BF_LO(u2.x) + a0) * 0.25f;
        float v1 = (BF_HI(u0.x) + BF_HI(u1.x) + BF_HI(u2.x) + a1) * 0.25f;
        float v2 = (BF_LO(u0.y) + BF_LO(u1.y) + BF_LO(u2.y) + a2) * 0.25f;
        float v3 = (BF_HI(u0.y) + BF_HI(u1.y) + BF_HI(u2.y) + a3) * 0.25f;
#undef BF_LO
#undef BF_HI

        float ss = v0 * v0 + v1 * v1 + v2 * v2 + v3 * v3;
        // reduce across the 16 dim-lanes (offsets stay inside lanes 0..15)
        ss += __shfl_xor(ss, 1);
        ss += __shfl_xor(ss, 2);
        ss += __shfl_xor(ss, 4);
        ss += __shfl_xor(ss, 8);
        float scale = 1.0f / fmaxf(sqrtf(ss), 1e-12f);

        float4 r = { v0 * scale, v1 * scale, v2 * scale, v3 * scale };
        *(float4*)(outp + o) = r;
    }
    if (blockIdx.x == 0 && threadIdx.x == 0)
        outp[(size_t)N_NODES * EMBED_DIM] = 0.0f;  // align_loss
}

// ---------------------------------------------------------------------------
extern "C" void kernel_launch(void* const* d_in, const int* in_sizes, int n_in,
                              void* d_out, int out_size, void* d_ws, size_t ws_size,
                              hipStream_t stream) {
    const float* user_w     = (const float*)d_in[0];
    const float* artist_w   = (const float*)d_in[1];
    const float* album_w    = (const float*)d_in[2];
    const float* audio      = (const float*)d_in[3];
    const float* edge_attr  = (const float*)d_in[4];
    const float* ew         = (const float*)d_in[5];
    const float* w1         = (const float*)d_in[6];
    const float* b1         = (const float*)d_in[7];
    const float* w2         = (const float*)d_in[8];
    const float* b2         = (const float*)d_in[9];
    const int*   edge_index = (const int*)d_in[10];
    const int*   artist_ids = (const int*)d_in[11];
    const int*   album_ids  = (const int*)d_in[12];
    float* out = (float*)d_out;

    float* ws = (float*)d_ws;
    // Persistent regions (offsets in float units):
    unsigned short* x0 = (unsigned short*)ws;                // 9.6M bf16
    unsigned short* x1 = (unsigned short*)(ws + 4800000);    // 9.6M bf16
    unsigned short* x2 = (unsigned short*)(ws + 9600000);    // 9.6M bf16
    int*  row_ptr  = (int*)(ws + 14400000);                  // 150001 ints
    int2* csr_pair = (int2*)(ws + 14560000);                 // 1.25M pairs (8B-aligned)
    float* dinv    = ws + 17060000;                          // 150k floats
    // Transients aliased into x0/x1 region (dead before init_x writes x0):
    int*   cnt     = (int*)ws;                               // 150k ints
    int*   rank    = (int*)(ws + 150000);                    // 1.25M ints
    int*   part    = (int*)(ws + 1400000);                   // 147 ints
    int*   baseoff = (int*)(ws + 1401000);                   // 147 ints

    const int B = 256;
    const int egrid = (NUM_EDGES + B - 1) / B;
    const int ngrid   = (N_NODES * EMBED_DIM) / B;   // wave-per-node grids
    const int ngrid16 = (N_NODES * 16) / B;          // 16-lane-per-node grids

    hipMemsetAsync(cnt, 0, N_NODES * sizeof(int), stream);

    hist_rank<<<egrid, B, 0, stream>>>(edge_index, cnt, rank);

    scan_partial<<<SCAN_NB, SCAN_B, 0, stream>>>(cnt, part);
    scan_offsets<<<1, 256, 0, stream>>>(part, baseoff);
    scan_apply<<<SCAN_NB, SCAN_B, 0, stream>>>(cnt, baseoff, row_ptr);

    mlp_scatter<<<egrid, B, 0, stream>>>(
        edge_attr, ew, w1, b1, w2, b2, edge_index, rank, row_ptr, csr_pair);

    deg_dinv_csr<<<ngrid16, B, 0, stream>>>(row_ptr, csr_pair, dinv);
    csr_scale<<<ngrid16, B, 0, stream>>>(row_ptr, dinv, csr_pair);

    init_x<<<ngrid, B, 0, stream>>>(
        user_w, artist_w, album_w, audio, artist_ids, album_ids,
        (__hip_bfloat16*)x0);

    propagate_mid<<<ngrid, B, 0, stream>>>(row_ptr, csr_pair, x0, x1);
    propagate_mid<<<ngrid, B, 0, stream>>>(row_ptr, csr_pair, x1, x2);
    propagate_final<<<ngrid, B, 0, stream>>>(row_ptr, csr_pair, x0, x1, x2, out);
}

// Round 2
// 409.060 us; speedup vs baseline: 1.1691x; 1.1365x over previous
//
#include <hip/hip_runtime.h>
#include <hip/hip_bf16.h>
#include <math.h>

#define NUM_USERS  100000
#define NUM_ITEMS  50000
#define N_NODES    150000
#define EMBED_DIM  64
#define NUM_EDGES  1250000
#define MLP_HID    32
#define SCAN_B     1024
#define SCAN_NB    ((N_NODES + SCAN_B - 1) / SCAN_B)   // 147
#define NPW        4   // nodes per wave in propagate kernels

// ---------------------------------------------------------------------------
// Kernel 1: histogram of cols + within-bucket rank (atomic return value IS
// the rank -> downstream scatter needs no atomics).
// ---------------------------------------------------------------------------
__global__ void hist_rank(const int* __restrict__ edge_index,
                          int* __restrict__ cnt,
                          int* __restrict__ rank) {
    int e = blockIdx.x * blockDim.x + threadIdx.x;
    if (e >= NUM_EDGES) return;
    int c = edge_index[NUM_EDGES + e];
    rank[e] = atomicAdd(&cnt[c], 1);
}

// ---------------------------------------------------------------------------
// Device-wide exclusive scan of cnt -> row_ptr, 3 phases.
// ---------------------------------------------------------------------------
__global__ void scan_partial(const int* __restrict__ cnt,
                             int* __restrict__ part) {
    __shared__ int s[SCAN_B];
    int tid = threadIdx.x;
    int i = blockIdx.x * SCAN_B + tid;
    s[tid] = (i < N_NODES) ? cnt[i] : 0;
    __syncthreads();
#pragma unroll
    for (int off = SCAN_B / 2; off > 0; off >>= 1) {
        if (tid < off) s[tid] += s[tid + off];
        __syncthreads();
    }
    if (tid == 0) part[blockIdx.x] = s[0];
}

__global__ void scan_offsets(const int* __restrict__ part,
                             int* __restrict__ base_off) {
    __shared__ int s[256];
    int tid = threadIdx.x;
    int v = (tid < SCAN_NB) ? part[tid] : 0;
    s[tid] = v;
    __syncthreads();
#pragma unroll
    for (int off = 1; off < 256; off <<= 1) {
        int t = (tid >= off) ? s[tid - off] : 0;
        __syncthreads();
        s[tid] += t;
        __syncthreads();
    }
    if (tid < SCAN_NB) base_off[tid] = s[tid] - v;   // exclusive
}

__global__ void scan_apply(const int* __restrict__ cnt,
                           const int* __restrict__ base_off,
                           int* __restrict__ row_ptr) {
    __shared__ int s[SCAN_B];
    int tid = threadIdx.x;
    int i = blockIdx.x * SCAN_B + tid;
    int v = (i < N_NODES) ? cnt[i] : 0;
    s[tid] = v;
    __syncthreads();
    for (int off = 1; off < SCAN_B; off <<= 1) {
        int t = (tid >= off) ? s[tid - off] : 0;
        __syncthreads();
        s[tid] += t;
        __syncthreads();
    }
    if (i < N_NODES) row_ptr[i] = s[tid] - v + base_off[blockIdx.x];
    if (blockIdx.x == 0 && tid == 0) row_ptr[N_NODES] = NUM_EDGES;
}

// ---------------------------------------------------------------------------
// Kernel 2: per-edge MLP fused with ATOMIC-FREE CSR scatter.
// ---------------------------------------------------------------------------
__global__ void mlp_scatter(const float* __restrict__ edge_attr,
                            const float* __restrict__ ew,
                            const float* __restrict__ w1,
                            const float* __restrict__ b1,
                            const float* __restrict__ w2,
                            const float* __restrict__ b2,
                            const int*   __restrict__ edge_index,
                            const int*   __restrict__ rank,
                            const int*   __restrict__ row_ptr,
                            int2* __restrict__ csr_pair) {
    __shared__ float w1s[8 * MLP_HID];
    __shared__ float b1s[MLP_HID];
    __shared__ float w2s[MLP_HID];
    int tid = threadIdx.x;
    if (tid < 8 * MLP_HID) w1s[tid] = w1[tid];
    if (tid < MLP_HID) { b1s[tid] = b1[tid]; w2s[tid] = w2[tid]; }
    __syncthreads();

    int e = blockIdx.x * blockDim.x + tid;
    if (e >= NUM_EDGES) return;

    float ef[8];
#pragma unroll
    for (int k = 0; k < 7; ++k) ef[k] = edge_attr[e * 7 + k];
    ef[7] = ew[e];

    float s = b2[0];
#pragma unroll
    for (int j = 0; j < MLP_HID; ++j) {
        float h = b1s[j];
#pragma unroll
        for (int k = 0; k < 8; ++k) h = fmaf(ef[k], w1s[k * MLP_HID + j], h);
        h = fmaxf(h, 0.0f);
        s = fmaf(h, w2s[j], s);
    }
    float w = 1.0f / (1.0f + expf(-s));

    int r = edge_index[e];
    int c = edge_index[NUM_EDGES + e];
    int pos = row_ptr[c] + rank[e];
    int2 pr;
    pr.x = r;
    pr.y = __float_as_int(w);
    csr_pair[pos] = pr;
}

// ---------------------------------------------------------------------------
// deg[node] = segment sum of pair.w bucket; 16 lanes/node (avg deg 8.3).
// ---------------------------------------------------------------------------
__global__ void deg_dinv_csr(const int* __restrict__ row_ptr,
                             const int2* __restrict__ csr_pair,
                             float* __restrict__ dinv) {
    int t = blockIdx.x * blockDim.x + threadIdx.x;
    int node = t >> 4;
    int lane = t & 15;
    if (node >= N_NODES) return;
    int s = row_ptr[node], e = row_ptr[node + 1];
    float sum = 0.0f;
    for (int j = s + lane; j < e; j += 16) sum += __int_as_float(csr_pair[j].y);
    sum += __shfl_xor(sum, 8);
    sum += __shfl_xor(sum, 4);
    sum += __shfl_xor(sum, 2);
    sum += __shfl_xor(sum, 1);
    if (lane == 0)
        dinv[node] = (sum > 0.0f) ? rsqrtf(fmaxf(sum, 1e-30f)) : 0.0f;
}

// ---------------------------------------------------------------------------
// pair.w *= dinv[col] * dinv[pair.src]   16 lanes/node.
// ---------------------------------------------------------------------------
__global__ void csr_scale(const int* __restrict__ row_ptr,
                          const float* __restrict__ dinv,
                          int2* __restrict__ csr_pair) {
    int t = blockIdx.x * blockDim.x + threadIdx.x;
    int node = t >> 4;
    int lane = t & 15;
    if (node >= N_NODES) return;
    int s = row_ptr[node], e = row_ptr[node + 1];
    float dc = dinv[node];
    for (int j = s + lane; j < e; j += 16) {
        int2 p = csr_pair[j];
        p.y = __float_as_int(__int_as_float(p.y) * dc * dinv[p.x]);
        csr_pair[j] = p;
    }
}

// ---------------------------------------------------------------------------
// build x0: bf16 only.
// ---------------------------------------------------------------------------
__global__ void init_x(const float* __restrict__ user_w,
                       const float* __restrict__ artist_w,
                       const float* __restrict__ album_w,
                       const float* __restrict__ audio,
                       const int*   __restrict__ artist_ids,
                       const int*   __restrict__ album_ids,
                       __hip_bfloat16* __restrict__ x) {
    int t = blockIdx.x * blockDim.x + threadIdx.x;
    int row = t >> 6;
    int lane = t & 63;
    if (row >= N_NODES) return;

    float v;
    if (row < NUM_USERS) {
        v = user_w[row * EMBED_DIM + lane];
    } else {
        int r = row - NUM_USERS;
        int ar = artist_ids[r];
        int al = album_ids[r];
        v = audio[r * EMBED_DIM + lane]
          + 0.5f * (artist_w[ar * EMBED_DIM + lane] + album_w[al * EMBED_DIM + lane]);
    }
    float ss = v * v;
#pragma unroll
    for (int off = 32; off > 0; off >>= 1) ss += __shfl_xor(ss, off);
    float scale = 1.0f / fmaxf(sqrtf(ss), 1e-12f);
    x[row * EMBED_DIM + lane] = __float2bfloat16(v * scale);
}

// ---------------------------------------------------------------------------
// pull-mode propagation v3: one wave = NPW(4) consecutive nodes.
//  - row_ptr for all 5 boundaries loaded ONCE (coalesced + shfl broadcast)
//  - 4 edge slots x 16 dim-lanes; each iteration = 16 edges, slot eg owns the
//    contiguous quad [base+4*eg, base+4*eg+4) -> 4 INDEPENDENT uint2 gathers
//    in flight per iteration (was 1).
//  - next pair group (or next node's first group) prefetched before the FMAs,
//    so the rp->pair->gather chain only occurs once per wave.
//  Prefetch may run up to 16 pairs past rp[NPW]; csr_pair is followed by the
//  dinv region inside the workspace, so the read is harmless and the values
//  are discarded by the o* guards.
// ---------------------------------------------------------------------------
#define BF_LO(u) __uint_as_float((u) << 16)
#define BF_HI(u) __uint_as_float((u) & 0xffff0000u)

__global__ void propagate_mid(const int* __restrict__ row_ptr,
                              const int2* __restrict__ csr_pair,
                              const unsigned short* __restrict__ xin,
                              unsigned short* __restrict__ xout) {
    int wave = (blockIdx.x * blockDim.x + threadIdx.x) >> 6;
    int lane = threadIdx.x & 63;
    int node0 = wave * NPW;
    if (node0 >= N_NODES) return;

    int eg = lane >> 4;          // edge slot 0..3
    int dq = (lane & 15) << 2;   // dim quad start

    int rpv = row_ptr[node0 + (lane < NPW ? lane : NPW)];
    int rs0 = __shfl(rpv, 0);
    int rs1 = __shfl(rpv, 1);
    int rs2 = __shfl(rpv, 2);
    int rs3 = __shfl(rpv, 3);
    int rs4 = __shfl(rpv, 4);
    int rs[NPW + 1] = { rs0, rs1, rs2, rs3, rs4 };

    // prefetch node 0's first pair group
    int j = rs0 + (eg << 2);
    int2 p0 = csr_pair[j];
    int2 p1 = csr_pair[j + 1];
    int2 p2 = csr_pair[j + 2];
    int2 p3 = csr_pair[j + 3];

#pragma unroll
    for (int k = 0; k < NPW; ++k) {
        int base = rs[k];
        int e    = rs[k + 1];
        float a0 = 0, a1 = 0, a2 = 0, a3 = 0;

        while (true) {
            int idx = base + (eg << 2);
            bool o0 = idx     < e;
            bool o1 = idx + 1 < e;
            bool o2 = idx + 2 < e;
            bool o3 = idx + 3 < e;
            int   s0 = o0 ? p0.x : 0; float w0 = o0 ? __int_as_float(p0.y) : 0.0f;
            int   s1 = o1 ? p1.x : 0; float w1 = o1 ? __int_as_float(p1.y) : 0.0f;
            int   s2 = o2 ? p2.x : 0; float w2 = o2 ? __int_as_float(p2.y) : 0.0f;
            int   s3 = o3 ? p3.x : 0; float w3 = o3 ? __int_as_float(p3.y) : 0.0f;

            uint2 u0 = *(const uint2*)(xin + ((size_t)s0 << 6) + dq);
            uint2 u1 = *(const uint2*)(xin + ((size_t)s1 << 6) + dq);
            uint2 u2 = *(const uint2*)(xin + ((size_t)s2 << 6) + dq);
            uint2 u3 = *(const uint2*)(xin + ((size_t)s3 << 6) + dq);

            int  nbase = base + 16;
            bool more  = nbase < e;
            int  nj    = (more ? nbase : e) + (eg << 2);
            p0 = csr_pair[nj];
            p1 = csr_pair[nj + 1];
            p2 = csr_pair[nj + 2];
            p3 = csr_pair[nj + 3];

            a0 = fmaf(w0, BF_LO(u0.x), a0); a1 = fmaf(w0, BF_HI(u0.x), a1);
            a2 = fmaf(w0, BF_LO(u0.y), a2); a3 = fmaf(w0, BF_HI(u0.y), a3);
            a0 = fmaf(w1, BF_LO(u1.x), a0); a1 = fmaf(w1, BF_HI(u1.x), a1);
            a2 = fmaf(w1, BF_LO(u1.y), a2); a3 = fmaf(w1, BF_HI(u1.y), a3);
            a0 = fmaf(w2, BF_LO(u2.x), a0); a1 = fmaf(w2, BF_HI(u2.x), a1);
            a2 = fmaf(w2, BF_LO(u2.y), a2); a3 = fmaf(w2, BF_HI(u2.y), a3);
            a0 = fmaf(w3, BF_LO(u3.x), a0); a1 = fmaf(w3, BF_HI(u3.x), a1);
            a2 = fmaf(w3, BF_LO(u3.y), a2); a3 = fmaf(w3, BF_HI(u3.y), a3);

            if (!more) break;
            base = nbase;
        }

        a0 += __shfl_xor(a0, 16); a1 += __shfl_xor(a1, 16);
        a2 += __shfl_xor(a2, 16); a3 += __shfl_xor(a3, 16);
        a0 += __shfl_xor(a0, 32); a1 += __shfl_xor(a1, 32);
        a2 += __shfl_xor(a2, 32); a3 += __shfl_xor(a3, 32);

        if (eg == 0) {
            size_t o = ((size_t)(node0 + k) << 6) + dq;
            unsigned int b0 = (unsigned int)__bfloat16_as_ushort(__float2bfloat16(a0));
            unsigned int b1 = (unsigned int)__bfloat16_as_ushort(__float2bfloat16(a1));
            unsigned int b2 = (unsigned int)__bfloat16_as_ushort(__float2bfloat16(a2));
            unsigned int b3 = (unsigned int)__bfloat16_as_ushort(__float2bfloat16(a3));
            uint2 u;
            u.x = b0 | (b1 << 16);
            u.y = b2 | (b3 << 16);
            *(uint2*)(xout + o) = u;
        }
    }
}

// ---------------------------------------------------------------------------
// FINAL layer: gather from x2, then out = l2norm((x0+x1+x2+a)/4), f32.
// Same NPW-node wave structure.
// ---------------------------------------------------------------------------
__global__ void propagate_final(const int* __restrict__ row_ptr,
                                const int2* __restrict__ csr_pair,
                                const unsigned short* __restrict__ x0,
                                const unsigned short* __restrict__ x1,
                                const unsigned short* __restrict__ x2,
                                float* __restrict__ outp) {
    int wave = (blockIdx.x * blockDim.x + threadIdx.x) >> 6;
    int lane = threadIdx.x & 63;
    int node0 = wave * NPW;
    if (node0 >= N_NODES) return;

    int eg = lane >> 4;
    int dq = (lane & 15) << 2;

    int rpv = row_ptr[node0 + (lane < NPW ? lane : NPW)];
    int rs0 = __shfl(rpv, 0);
    int rs1 = __shfl(rpv, 1);
    int rs2 = __shfl(rpv, 2);
    int rs3 = __shfl(rpv, 3);
    int rs4 = __shfl(rpv, 4);
    int rs[NPW + 1] = { rs0, rs1, rs2, rs3, rs4 };

    int j = rs0 + (eg << 2);
    int2 p0 = csr_pair[j];
    int2 p1 = csr_pair[j + 1];
    int2 p2 = csr_pair[j + 2];
    int2 p3 = csr_pair[j + 3];

#pragma unroll
    for (int k = 0; k < NPW; ++k) {
        int base = rs[k];
        int e    = rs[k + 1];
        float a0 = 0, a1 = 0, a2 = 0, a3 = 0;

        while (true) {
            int idx = base + (eg << 2);
            bool o0 = idx     < e;
            bool o1 = idx + 1 < e;
            bool o2 = idx + 2 < e;
            bool o3 = idx + 3 < e;
            int   s0 = o0 ? p0.x : 0; float w0 = o0 ? __int_as_float(p0.y) : 0.0f;
            int   s1 = o1 ? p1.x : 0; float w1 = o1 ? __int_as_float(p1.y) : 0.0f;
            int   s2 = o2 ? p2.x : 0; float w2 = o2 ? __int_as_float(p2.y) : 0.0f;
            int   s3 = o3 ? p3.x : 0; float w3 = o3 ? __int_as_float(p3.y) : 0.0f;

            uint2 u0 = *(const uint2*)(x2 + ((size_t)s0 << 6) + dq);
            uint2 u1 = *(const uint2*)(x2 + ((size_t)s1 << 6) + dq);
            uint2 u2 = *(const uint2*)(x2 + ((size_t)s2 << 6) + dq);
            uint2 u3 = *(const uint2*)(x2 + ((size_t)s3 << 6) + dq);

            int  nbase = base + 16;
            bool more  = nbase < e;
            int  nj    = (more ? nbase : e) + (eg << 2);
            p0 = csr_pair[nj];
            p1 = csr_pair[nj + 1];
            p2 = csr_pair[nj + 2];
            p3 = csr_pair[nj + 3];

            a0 = fmaf(w0, BF_LO(u0.x), a0); a1 = fmaf(w0, BF_HI(u0.x), a1);
            a2 = fmaf(w0, BF_LO(u0.y), a2); a3 = fmaf(w0, BF_HI(u0.y), a3);
            a0 = fmaf(w1, BF_LO(u1.x), a0); a1 = fmaf(w1, BF_HI(u1.x), a1);
            a2 = fmaf(w1, BF_LO(u1.y), a2); a3 = fmaf(w1, BF_HI(u1.y), a3);
            a0 = fmaf(w2, BF_LO(u2.x), a0); a1 = fmaf(w2, BF_HI(u2.x), a1);
            a2 = fmaf(w2, BF_LO(u2.y), a2); a3 = fmaf(w2, BF_HI(u2.y), a3);
            a0 = fmaf(w3, BF_LO(u3.x), a0); a1 = fmaf(w3, BF_HI(u3.x), a1);
            a2 = fmaf(w3, BF_LO(u3.y), a2); a3 = fmaf(w3, BF_HI(u3.y), a3);

            if (!more) break;
            base = nbase;
        }

        a0 += __shfl_xor(a0, 16); a1 += __shfl_xor(a1, 16);
        a2 += __shfl_xor(a2, 16); a3 += __shfl_xor(a3, 16);
        a0 += __shfl_xor(a0, 32); a1 += __shfl_xor(a1, 32);
        a2 += __shfl_xor(a2, 32); a3 += __shfl_xor(a3, 32);

        if (eg == 0) {
            size_t o = ((size_t)(node0 + k) << 6) + dq;
            uint2 u0 = *(const uint2*)(x0 + o);
            uint2 u1 = *(const uint2*)(x1 + o);
            uint2 u2 = *(const uint2*)(x2 + o);

            float v0 = (BF_LO(u0.x) + BF_LO(u1.x) + BF_LO(u2.x) + a0) * 0.25f;
            float v1 = (BF_HI(u0.x) + BF_HI(u1.x) + BF_HI(u2.x) + a1) * 0.25f;
            float v2 = (BF_LO(u0.y) + BF_LO(u1.y) + BF_LO(u2.y) + a2) * 0.25f;
            float v3 = (BF_HI(u0.y) + BF_HI(u1.y) + BF_HI(u2.y) + a3) * 0.25f;

            float ss = v0 * v0 + v1 * v1 + v2 * v2 + v3 * v3;
            ss += __shfl_xor(ss, 1);
            ss += __shfl_xor(ss, 2);
            ss += __shfl_xor(ss, 4);
            ss += __shfl_xor(ss, 8);
            float scale = 1.0f / fmaxf(sqrtf(ss), 1e-12f);

            float4 r = { v0 * scale, v1 * scale, v2 * scale, v3 * scale };
            *(float4*)(outp + o) = r;
        }
    }
    if (blockIdx.x == 0 && threadIdx.x == 0)
        outp[(size_t)N_NODES * EMBED_DIM] = 0.0f;  // align_loss
}

#undef BF_LO
#undef BF_HI

// ---------------------------------------------------------------------------
extern "C" void kernel_launch(void* const* d_in, const int* in_sizes, int n_in,
                              void* d_out, int out_size, void* d_ws, size_t ws_size,
                              hipStream_t stream) {
    const float* user_w     = (const float*)d_in[0];
    const float* artist_w   = (const float*)d_in[1];
    const float* album_w    = (const float*)d_in[2];
    const float* audio      = (const float*)d_in[3];
    const float* edge_attr  = (const float*)d_in[4];
    const float* ew         = (const float*)d_in[5];
    const float* w1         = (const float*)d_in[6];
    const float* b1         = (const float*)d_in[7];
    const float* w2         = (const float*)d_in[8];
    const float* b2         = (const float*)d_in[9];
    const int*   edge_index = (const int*)d_in[10];
    const int*   artist_ids = (const int*)d_in[11];
    const int*   album_ids  = (const int*)d_in[12];
    float* out = (float*)d_out;

    float* ws = (float*)d_ws;
    // Persistent regions (offsets in float units):
    unsigned short* x0 = (unsigned short*)ws;                // 9.6M bf16
    unsigned short* x1 = (unsigned short*)(ws + 4800000);    // 9.6M bf16
    unsigned short* x2 = (unsigned short*)(ws + 9600000);    // 9.6M bf16
    int*  row_ptr  = (int*)(ws + 14400000);                  // 150001 ints
    int2* csr_pair = (int2*)(ws + 14560000);                 // 1.25M pairs (8B-aligned)
    float* dinv    = ws + 17060000;                          // 150k floats
    // Transients aliased into x0/x1 region (dead before init_x writes x0):
    int*   cnt     = (int*)ws;                               // 150k ints
    int*   rank    = (int*)(ws + 150000);                    // 1.25M ints
    int*   part    = (int*)(ws + 1400000);                   // 147 ints
    int*   baseoff = (int*)(ws + 1401000);                   // 147 ints

    const int B = 256;
    const int egrid = (NUM_EDGES + B - 1) / B;
    const int ngrid   = (N_NODES * EMBED_DIM) / B;           // wave-per-node grids
    const int ngrid16 = (N_NODES * 16) / B;                  // 16-lane-per-node grids
    const int pgrid   = (N_NODES / NPW * 64) / B;            // NPW-nodes-per-wave grids

    hipMemsetAsync(cnt, 0, N_NODES * sizeof(int), stream);

    hist_rank<<<egrid, B, 0, stream>>>(edge_index, cnt, rank);

    scan_partial<<<SCAN_NB, SCAN_B, 0, stream>>>(cnt, part);
    scan_offsets<<<1, 256, 0, stream>>>(part, baseoff);
    scan_apply<<<SCAN_NB, SCAN_B, 0, stream>>>(cnt, baseoff, row_ptr);

    mlp_scatter<<<egrid, B, 0, stream>>>(
        edge_attr, ew, w1, b1, w2, b2, edge_index, rank, row_ptr, csr_pair);

    deg_dinv_csr<<<ngrid16, B, 0, stream>>>(row_ptr, csr_pair, dinv);
    csr_scale<<<ngrid16, B, 0, stream>>>(row_ptr, dinv, csr_pair);

    init_x<<<ngrid, B, 0, stream>>>(
        user_w, artist_w, album_w, audio, artist_ids, album_ids,
        (__hip_bfloat16*)x0);

    propagate_mid<<<pgrid, B, 0, stream>>>(row_ptr, csr_pair, x0, x1);
    propagate_mid<<<pgrid, B, 0, stream>>>(row_ptr, csr_pair, x1, x2);
    propagate_final<<<pgrid, B, 0, stream>>>(row_ptr, csr_pair, x0, x1, x2, out);
}